// Round 10
// baseline (125.439 us; speedup 1.0000x reference)
//
#include <hip/hip_runtime.h>

#define N_ 64
#define C_ 4
#define D_ 2048
#define K_ 64
#define O_ 256
#define L_ 1985
#define XCOPY 2116         // stride of shifted bf16 copies (shorts)
#define OPITCH 2020        // staging pitch (floats): mod 32 == 4 (bank spread)
#define NTILE 125          // ceil(L_/16)

typedef __attribute__((ext_vector_type(8))) short s16x8;
typedef __attribute__((ext_vector_type(4))) float f32x4;

// lgkmcnt-only barrier: global stores stay in flight across it
#define BAR_LGKM() do { \
    asm volatile("s_waitcnt lgkmcnt(0)\n\ts_barrier" ::: "memory"); \
    __builtin_amdgcn_sched_barrier(0); \
} while (0)

__device__ __forceinline__ unsigned short f2bf(float f) {
    union { float f; unsigned u; } v; v.f = f;
    unsigned u = v.u;
    u += 0x7fffu + ((u >> 16) & 1u);   // RNE
    return (unsigned short)(u >> 16);
}

// weight (O,C,K) fp32 -> bf16, plus yn/64 (pre-scaled norm)
__global__ __launch_bounds__(256) void prep_w(const float* __restrict__ w,
                                              unsigned short* __restrict__ wb,
                                              float* __restrict__ ynK) {
    int o = blockIdx.x;
    int tid = threadIdx.x;
    int c = tid >> 6, k = tid & 63;
    size_t idx = (size_t)(o * C_ + c) * K_ + k;
    float v = w[idx];
    wb[idx] = f2bf(v);
    float s = v * v;
    for (int off = 32; off > 0; off >>= 1) s += __shfl_down(s, off, 64);
    if (k == 0) ynK[o * C_ + c] = s * 0.015625f;
}

// One block per (n,c), 16 waves, 16 stages. Drain: the whole block copies one
// row at a time in strict address order -> one compact ~8KB write window per
// block (256 sequential streams chip-wide instead of 4096 scattered ones).
__global__ __launch_bounds__(1024) void shapelet_main(const float* __restrict__ x,
                                                      const unsigned short* __restrict__ wb,
                                                      const float* __restrict__ ynK,
                                                      float* __restrict__ out) {
    __shared__ __align__(16) unsigned short xs[4][XCOPY]; // xs[s][i] = bf16(x[i+s])
    __shared__ float xn[D_];                              // window sumsq / 64
    __shared__ __align__(16) float ost[16 * OPITCH];      // staging (scratch in prologue)

    int nc = blockIdx.x;
    int c = nc & (C_ - 1);
    const float* xrow = x + (size_t)nc * D_;
    int tid = threadIdx.x;

    float* z    = ost;                 // [0..2111]  x^2, zero-padded
    float* pre  = ost + 2176;          // [m*16+b]   in-block prefix sums (m<132)
    float* S16v = ost + 2176 + 2112;   // [m]        16-elem block sums

    // phase 1: bf16 copies + squares straight from global (row is L2-hot)
    for (int i = tid; i < 2112; i += 1024) {
        float v = (i < D_) ? xrow[i] : 0.f;
        z[i] = v * v;
        unsigned short b = f2bf(v);
        #pragma unroll
        for (int s = 0; s < 4; ++s) { int j = i - s; if (j >= 0) xs[s][j] = b; }
    }
    __syncthreads();
    // phase 2: 16-elem block sums + in-block prefixes (132 blocks)
    if (tid < 132) {
        float run = 0.f;
        int base = tid * 16;
        #pragma unroll
        for (int j = 0; j < 16; ++j) { pre[base + j] = run; run += z[base + j]; }
        S16v[tid] = run;
    }
    __syncthreads();
    // phase 3: xn[l] = (suffix(a,b) + S16[a+1..a+3] + prefix(a+4,b)) / 64
    for (int l = tid; l < D_; l += 1024) {
        int a = l >> 4, b = l & 15;
        float s = S16v[a] - pre[a * 16 + b] + S16v[a + 1] + S16v[a + 2]
                + S16v[a + 3] + pre[(a + 4) * 16 + b];
        xn[l] = s * 0.015625f;
    }
    __syncthreads();

    int wave = tid >> 6, lane = tid & 63, lr = lane & 15, hi = lane >> 4;
    const unsigned short* xbase = &xs[lr & 3][(lr & ~3) + hi * 8];

    int s4 = tid * 4;
    bool act = (s4 + 4 <= L_);        // tids 0..495 move a dwordx4
    bool tl  = (tid == 496);          // element 1984

    for (int st = 0; st < 16; ++st) {
        // ---- compute stage st: 16 o-rows x full L into ost ----
        int o = st * 16 + lr;
        const s16x8* wp = reinterpret_cast<const s16x8*>(
            wb + ((size_t)o * C_ + c) * K_ + hi * 8);
        s16x8 w0 = wp[0];          // k 0..31 slice
        s16x8 w1 = wp[4];          // k 32..63 slice
        float ynKv = ynK[o * C_ + c];

        #pragma unroll
        for (int i = 0; i < 8; ++i) {
            int t = wave + i * 16;
            int tc = t > 124 ? 124 : t;          // clamp: reads stay in-bounds
            int l0t = tc * 16;
            union { unsigned long long u[2]; s16x8 v; } a0, a1;
            const unsigned long long* p0 = (const unsigned long long*)(xbase + l0t);
            a0.u[0] = p0[0]; a0.u[1] = p0[1];
            const unsigned long long* p1 = (const unsigned long long*)(xbase + l0t + 32);
            a1.u[0] = p1[0]; a1.u[1] = p1[1];
            f32x4 acc = {0.f, 0.f, 0.f, 0.f};
            acc = __builtin_amdgcn_mfma_f32_16x16x32_bf16(a0.v, w0, acc, 0, 0, 0);
            acc = __builtin_amdgcn_mfma_f32_16x16x32_bf16(a1.v, w1, acc, 0, 0, 0);
            f32x4 xv = *reinterpret_cast<const f32x4*>(&xn[l0t + hi * 4]);
            f32x4 r;
            #pragma unroll
            for (int j = 0; j < 4; ++j)
                r[j] = fmaxf(fmaf(acc[j], -0.03125f, xv[j] + ynKv), 0.f);
            if (t < NTILE)
                *reinterpret_cast<f32x4*>(&ost[lr * OPITCH + l0t + hi * 4]) = r;
        }
        BAR_LGKM();   // staging complete; prior-stage stores still in flight

        // ---- drain: block-wide address-ordered sweep, one row at a time ----
        float* gb0 = out + ((size_t)nc * O_ + st * 16) * (size_t)L_;
        #pragma unroll 4
        for (int r = 0; r < 16; ++r) {
            const float* src = &ost[r * OPITCH];
            float* gb = gb0 + (size_t)r * L_;
            if (act) {
                f32x4 v = *reinterpret_cast<const f32x4*>(src + s4);  // aligned b128
                __builtin_memcpy(gb + s4, &v, 16);                    // dwordx4
            } else if (tl) {
                gb[L_ - 1] = src[L_ - 1];
            }
        }
        BAR_LGKM();   // drain reads done -> ost reusable; stores in flight
    }
}

extern "C" void kernel_launch(void* const* d_in, const int* in_sizes, int n_in,
                              void* d_out, int out_size, void* d_ws, size_t ws_size,
                              hipStream_t stream) {
    const float* x = (const float*)d_in[0];
    const float* w = (const float*)d_in[1];
    float* out = (float*)d_out;

    unsigned short* wb = (unsigned short*)d_ws;                     // 128 KiB
    float* ynK = (float*)((char*)d_ws + (size_t)O_ * C_ * K_ * 2);  // 4 KiB

    prep_w<<<O_, 256, 0, stream>>>(w, wb, ynK);
    shapelet_main<<<N_ * C_, 1024, 0, stream>>>(x, wb, ynK, out);
}

// Round 11
// 121.498 us; speedup vs baseline: 1.0324x; 1.0324x over previous
//
#include <hip/hip_runtime.h>

#define N_ 64
#define C_ 4
#define D_ 2048
#define K_ 64
#define O_ 256
#define L_ 1985
#define XCOPY 2116         // stride of shifted bf16 copies (shorts)
#define OPA 1000           // staging pitch half-A (floats)
#define OPB 1008           // staging pitch half-B (floats)
#define LA 992             // half-A length (l 0..991), 62 tiles
#define LB2 993            // half-B length (l 992..1984), 63 tiles

typedef __attribute__((ext_vector_type(8))) short s16x8;
typedef __attribute__((ext_vector_type(4))) float f32x4;

// lgkmcnt-only barrier: global stores stay in flight across it
#define BAR_LGKM() do { \
    asm volatile("s_waitcnt lgkmcnt(0)\n\ts_barrier" ::: "memory"); \
    __builtin_amdgcn_sched_barrier(0); \
} while (0)

__device__ __forceinline__ unsigned short f2bf(float f) {
    union { float f; unsigned u; } v; v.f = f;
    unsigned u = v.u;
    u += 0x7fffu + ((u >> 16) & 1u);   // RNE
    return (unsigned short)(u >> 16);
}

__global__ __launch_bounds__(256) void prep_w(const float* __restrict__ w,
                                              unsigned short* __restrict__ wb,
                                              float* __restrict__ ynK) {
    int o = blockIdx.x;
    int tid = threadIdx.x;
    int c = tid >> 6, k = tid & 63;
    size_t idx = (size_t)(o * C_ + c) * K_ + k;
    float v = w[idx];
    wb[idx] = f2bf(v);
    float s = v * v;
    for (int off = 32; off > 0; off >>= 1) s += __shfl_down(s, off, 64);
    if (k == 0) ynK[o * C_ + c] = s * 0.015625f;
}

// One block per (n,c), 16 waves. L split into halves A/B with separate LDS
// staging buffers; per stage: [compute A(st) + drain B(st-1)] | bar |
// [compute B(st) + drain A(st)] | bar.  Compute and HBM drain run
// CONCURRENTLY in each phase (different buffers), no store pinning.
__global__ __launch_bounds__(1024) void shapelet_main(const float* __restrict__ x,
                                                      const unsigned short* __restrict__ wb,
                                                      const float* __restrict__ ynK,
                                                      float* __restrict__ out) {
    __shared__ __align__(16) unsigned short xs[4][XCOPY]; // xs[s][i] = bf16(x[i+s])
    __shared__ float xn[D_];                              // window sumsq / 64
    __shared__ __align__(16) float ostA[16 * OPA];        // half-A staging (+prologue scratch)
    __shared__ __align__(16) float ostB[16 * OPB];        // half-B staging

    int nc = blockIdx.x;
    int c = nc & (C_ - 1);
    const float* xrow = x + (size_t)nc * D_;
    int tid = threadIdx.x;

    float* z    = ostA;                 // [0..2111]  x^2, zero-padded
    float* pre  = ostA + 2176;          // in-block prefix sums
    float* S16v = ostA + 2176 + 2112;   // 16-elem block sums

    // prologue: bf16 copies + squares straight from global
    for (int i = tid; i < 2112; i += 1024) {
        float v = (i < D_) ? xrow[i] : 0.f;
        z[i] = v * v;
        unsigned short b = f2bf(v);
        #pragma unroll
        for (int s = 0; s < 4; ++s) { int j = i - s; if (j >= 0) xs[s][j] = b; }
    }
    __syncthreads();
    if (tid < 132) {
        float run = 0.f;
        int base = tid * 16;
        #pragma unroll
        for (int j = 0; j < 16; ++j) { pre[base + j] = run; run += z[base + j]; }
        S16v[tid] = run;
    }
    __syncthreads();
    for (int l = tid; l < D_; l += 1024) {
        int a = l >> 4, b = l & 15;
        float s = S16v[a] - pre[a * 16 + b] + S16v[a + 1] + S16v[a + 2]
                + S16v[a + 3] + pre[(a + 4) * 16 + b];
        xn[l] = s * 0.015625f;
    }
    __syncthreads();

    int wave = tid >> 6, lane = tid & 63, lr = lane & 15, hi = lane >> 4;
    const unsigned short* xbase = &xs[lr & 3][(lr & ~3) + hi * 8];

    for (int st = 0; st < 16; ++st) {
        int o = st * 16 + lr;
        const s16x8* wp = reinterpret_cast<const s16x8*>(
            wb + ((size_t)o * C_ + c) * K_ + hi * 8);
        s16x8 w0 = wp[0];
        s16x8 w1 = wp[4];
        float ynKv = ynK[o * C_ + c];

        // ---- phase 1: compute half-A of stage st ----
        #pragma unroll
        for (int i = 0; i < 4; ++i) {
            int t = wave + i * 16;
            if (t < 62) {
                int l0t = t * 16;
                union { unsigned long long u[2]; s16x8 v; } a0, a1;
                const unsigned long long* p0 = (const unsigned long long*)(xbase + l0t);
                a0.u[0] = p0[0]; a0.u[1] = p0[1];
                const unsigned long long* p1 = (const unsigned long long*)(xbase + l0t + 32);
                a1.u[0] = p1[0]; a1.u[1] = p1[1];
                f32x4 acc = {0.f, 0.f, 0.f, 0.f};
                acc = __builtin_amdgcn_mfma_f32_16x16x32_bf16(a0.v, w0, acc, 0, 0, 0);
                acc = __builtin_amdgcn_mfma_f32_16x16x32_bf16(a1.v, w1, acc, 0, 0, 0);
                f32x4 xv = *reinterpret_cast<const f32x4*>(&xn[l0t + hi * 4]);
                f32x4 r;
                #pragma unroll
                for (int j = 0; j < 4; ++j)
                    r[j] = fmaxf(fmaf(acc[j], -0.03125f, xv[j] + ynKv), 0.f);
                *reinterpret_cast<f32x4*>(&ostA[lr * OPA + l0t + hi * 4]) = r;
            }
        }
        // ---- concurrently: drain half-B of stage st-1 ----
        if (st > 0) {
            float* gb = out + ((size_t)nc * O_ + (st - 1) * 16 + wave) * L_ + LA;
            const float* src = &ostB[wave * OPB];
            for (int pos = lane * 4; pos + 4 <= LB2; pos += 256) {
                f32x4 v = *reinterpret_cast<const f32x4*>(src + pos);
                __builtin_memcpy(gb + pos, &v, 16);
            }
            if (lane == 0) gb[LB2 - 1] = src[LB2 - 1];
        }
        BAR_LGKM();

        // ---- phase 2: compute half-B of stage st ----
        #pragma unroll
        for (int i = 0; i < 4; ++i) {
            int t = 62 + wave + i * 16;
            int tc = t > 124 ? 124 : t;
            int l0t = tc * 16;
            union { unsigned long long u[2]; s16x8 v; } a0, a1;
            const unsigned long long* p0 = (const unsigned long long*)(xbase + l0t);
            a0.u[0] = p0[0]; a0.u[1] = p0[1];
            const unsigned long long* p1 = (const unsigned long long*)(xbase + l0t + 32);
            a1.u[0] = p1[0]; a1.u[1] = p1[1];
            f32x4 acc = {0.f, 0.f, 0.f, 0.f};
            acc = __builtin_amdgcn_mfma_f32_16x16x32_bf16(a0.v, w0, acc, 0, 0, 0);
            acc = __builtin_amdgcn_mfma_f32_16x16x32_bf16(a1.v, w1, acc, 0, 0, 0);
            f32x4 xv = *reinterpret_cast<const f32x4*>(&xn[l0t + hi * 4]);
            f32x4 r;
            #pragma unroll
            for (int j = 0; j < 4; ++j)
                r[j] = fmaxf(fmaf(acc[j], -0.03125f, xv[j] + ynKv), 0.f);
            if (t < 125)
                *reinterpret_cast<f32x4*>(&ostB[lr * OPB + (tc - 62) * 16 + hi * 4]) = r;
        }
        // ---- concurrently: drain half-A of stage st ----
        {
            float* gb = out + ((size_t)nc * O_ + st * 16 + wave) * L_;
            const float* src = &ostA[wave * OPA];
            for (int pos = lane * 4; pos + 4 <= LA; pos += 256) {
                f32x4 v = *reinterpret_cast<const f32x4*>(src + pos);
                __builtin_memcpy(gb + pos, &v, 16);
            }
        }
        BAR_LGKM();
    }

    // final drain: half-B of stage 15
    {
        float* gb = out + ((size_t)nc * O_ + 15 * 16 + wave) * L_ + LA;
        const float* src = &ostB[wave * OPB];
        for (int pos = lane * 4; pos + 4 <= LB2; pos += 256) {
            f32x4 v = *reinterpret_cast<const f32x4*>(src + pos);
            __builtin_memcpy(gb + pos, &v, 16);
        }
        if (lane == 0) gb[LB2 - 1] = src[LB2 - 1];
    }
}

extern "C" void kernel_launch(void* const* d_in, const int* in_sizes, int n_in,
                              void* d_out, int out_size, void* d_ws, size_t ws_size,
                              hipStream_t stream) {
    const float* x = (const float*)d_in[0];
    const float* w = (const float*)d_in[1];
    float* out = (float*)d_out;

    unsigned short* wb = (unsigned short*)d_ws;                     // 128 KiB
    float* ynK = (float*)((char*)d_ws + (size_t)O_ * C_ * K_ * 2);  // 4 KiB

    prep_w<<<O_, 256, 0, stream>>>(w, wb, ynK);
    shapelet_main<<<N_ * C_, 1024, 0, stream>>>(x, wb, ynK, out);
}

// Round 12
// 116.503 us; speedup vs baseline: 1.0767x; 1.0429x over previous
//
#include <hip/hip_runtime.h>

#define N_ 64
#define C_ 4
#define D_ 2048
#define K_ 64
#define O_ 256
#define L_ 1985
#define XCOPY 2116         // stride of shifted bf16 copies (shorts)
#define SPITCH 2012        // bf16 staging pitch (shorts): >=2000, bank-spread
#define NTILE 125          // ceil(L_/16)

typedef __attribute__((ext_vector_type(8))) short s16x8;
typedef __attribute__((ext_vector_type(4))) float f32x4;

// lgkmcnt-only barrier: global stores stay in flight across it
#define BAR_LGKM() do { \
    asm volatile("s_waitcnt lgkmcnt(0)\n\ts_barrier" ::: "memory"); \
    __builtin_amdgcn_sched_barrier(0); \
} while (0)

__device__ __forceinline__ unsigned short f2bf(float f) {
    union { float f; unsigned u; } v; v.f = f;
    unsigned u = v.u;
    u += 0x7fffu + ((u >> 16) & 1u);   // RNE
    return (unsigned short)(u >> 16);
}

__device__ __forceinline__ float bf2f(unsigned short b) {
    union { unsigned u; float f; } v;
    v.u = (unsigned)b << 16;
    return v.f;
}

// weight (O,C,K) fp32 -> bf16, plus yn/64 (pre-scaled norm)
__global__ __launch_bounds__(256) void prep_w(const float* __restrict__ w,
                                              unsigned short* __restrict__ wb,
                                              float* __restrict__ ynK) {
    int o = blockIdx.x;
    int tid = threadIdx.x;
    int c = tid >> 6, k = tid & 63;
    size_t idx = (size_t)(o * C_ + c) * K_ + k;
    float v = w[idx];
    wb[idx] = f2bf(v);
    float s = v * v;
    for (int off = 32; off > 0; off >>= 1) s += __shfl_down(s, off, 64);
    if (k == 0) ynK[o * C_ + c] = s * 0.015625f;
}

// One block per (n,c), 16 waves. bf16 double-buffered staging -> ONE barrier
// per stage: compute band st into stg[p] while draining band st-1 from
// stg[p^1]. Halves barrier count (33 -> 17) and breaks the chip-wide
// compute/drain convoy.
__global__ __launch_bounds__(1024) void shapelet_main(const float* __restrict__ x,
                                                      const unsigned short* __restrict__ wb,
                                                      const float* __restrict__ ynK,
                                                      float* __restrict__ out) {
    __shared__ __align__(16) unsigned short xs[4][XCOPY]; // xs[s][i] = bf16(x[i+s])
    __shared__ float xn[D_];                              // window sumsq / 64
    __shared__ __align__(16) unsigned short stg[2][16 * SPITCH]; // bf16 staging x2

    int nc = blockIdx.x;
    int c = nc & (C_ - 1);
    const float* xrow = x + (size_t)nc * D_;
    int tid = threadIdx.x;

    float* z    = (float*)stg;          // [0..2111]  x^2, zero-padded
    float* pre  = (float*)stg + 2176;   // in-block prefix sums
    float* S16v = (float*)stg + 4288;   // 16-elem block sums

    // prologue: bf16 copies + squares straight from global (row is L2-hot)
    for (int i = tid; i < 2112; i += 1024) {
        float v = (i < D_) ? xrow[i] : 0.f;
        z[i] = v * v;
        unsigned short b = f2bf(v);
        #pragma unroll
        for (int s = 0; s < 4; ++s) { int j = i - s; if (j >= 0) xs[s][j] = b; }
    }
    __syncthreads();
    if (tid < 132) {
        float run = 0.f;
        int base = tid * 16;
        #pragma unroll
        for (int j = 0; j < 16; ++j) { pre[base + j] = run; run += z[base + j]; }
        S16v[tid] = run;
    }
    __syncthreads();
    for (int l = tid; l < D_; l += 1024) {
        int a = l >> 4, b = l & 15;
        float s = S16v[a] - pre[a * 16 + b] + S16v[a + 1] + S16v[a + 2]
                + S16v[a + 3] + pre[(a + 4) * 16 + b];
        xn[l] = s * 0.015625f;
    }
    __syncthreads();

    int wave = tid >> 6, lane = tid & 63, lr = lane & 15, hi = lane >> 4;
    const unsigned short* xbase = &xs[lr & 3][(lr & ~3) + hi * 8];
    int dj = lane;

    for (int st = 0; st < 16; ++st) {
        int p = st & 1;
        // ---- compute band st into stg[p] (bf16) ----
        int o = st * 16 + lr;
        const s16x8* wp = reinterpret_cast<const s16x8*>(
            wb + ((size_t)o * C_ + c) * K_ + hi * 8);
        s16x8 w0 = wp[0];
        s16x8 w1 = wp[4];
        float ynKv = ynK[o * C_ + c];

        #pragma unroll
        for (int i = 0; i < 8; ++i) {
            int t = wave + i * 16;
            int tc = t > 124 ? 124 : t;          // clamp: reads stay in-bounds
            int l0t = tc * 16;
            union { unsigned long long u[2]; s16x8 v; } a0, a1;
            const unsigned long long* p0 = (const unsigned long long*)(xbase + l0t);
            a0.u[0] = p0[0]; a0.u[1] = p0[1];
            const unsigned long long* p1 = (const unsigned long long*)(xbase + l0t + 32);
            a1.u[0] = p1[0]; a1.u[1] = p1[1];
            f32x4 acc = {0.f, 0.f, 0.f, 0.f};
            acc = __builtin_amdgcn_mfma_f32_16x16x32_bf16(a0.v, w0, acc, 0, 0, 0);
            acc = __builtin_amdgcn_mfma_f32_16x16x32_bf16(a1.v, w1, acc, 0, 0, 0);
            f32x4 xv = *reinterpret_cast<const f32x4*>(&xn[l0t + hi * 4]);
            float r0 = fmaxf(fmaf(acc[0], -0.03125f, xv[0] + ynKv), 0.f);
            float r1 = fmaxf(fmaf(acc[1], -0.03125f, xv[1] + ynKv), 0.f);
            float r2 = fmaxf(fmaf(acc[2], -0.03125f, xv[2] + ynKv), 0.f);
            float r3 = fmaxf(fmaf(acc[3], -0.03125f, xv[3] + ynKv), 0.f);
            unsigned long long pk =
                  (unsigned long long)f2bf(r0)
                | ((unsigned long long)f2bf(r1) << 16)
                | ((unsigned long long)f2bf(r2) << 32)
                | ((unsigned long long)f2bf(r3) << 48);
            if (t < NTILE)
                *(unsigned long long*)&stg[p][lr * SPITCH + l0t + hi * 4] = pk;  // ds_write_b64
        }

        // ---- concurrently: drain band st-1 from stg[p^1] ----
        if (st > 0) {
            float* gb = out + ((size_t)nc * O_ + (st - 1) * 16 + wave) * L_;
            const unsigned short* src = &stg[p ^ 1][wave * SPITCH];
            #pragma unroll
            for (int q = 0; q < 8; ++q) {
                int pos = dj * 4 + q * 256;
                if (pos + 4 <= L_) {
                    unsigned long long dv = *(const unsigned long long*)(src + pos); // ds_read_b64
                    f32x4 v;
                    v[0] = bf2f((unsigned short)(dv));
                    v[1] = bf2f((unsigned short)(dv >> 16));
                    v[2] = bf2f((unsigned short)(dv >> 32));
                    v[3] = bf2f((unsigned short)(dv >> 48));
                    __builtin_memcpy(gb + pos, &v, 16);   // dwordx4
                }
            }
            if (dj == 0) gb[L_ - 1] = bf2f(src[L_ - 1]);
        }
        BAR_LGKM();   // single barrier: stg[p] complete AND stg[p^1] reads done
    }

    // final drain: band 15 (in stg[1])
    {
        float* gb = out + ((size_t)nc * O_ + 15 * 16 + wave) * L_;
        const unsigned short* src = &stg[1][wave * SPITCH];
        #pragma unroll
        for (int q = 0; q < 8; ++q) {
            int pos = dj * 4 + q * 256;
            if (pos + 4 <= L_) {
                unsigned long long dv = *(const unsigned long long*)(src + pos);
                f32x4 v;
                v[0] = bf2f((unsigned short)(dv));
                v[1] = bf2f((unsigned short)(dv >> 16));
                v[2] = bf2f((unsigned short)(dv >> 32));
                v[3] = bf2f((unsigned short)(dv >> 48));
                __builtin_memcpy(gb + pos, &v, 16);
            }
        }
        if (dj == 0) gb[L_ - 1] = bf2f(src[L_ - 1]);
    }
}

extern "C" void kernel_launch(void* const* d_in, const int* in_sizes, int n_in,
                              void* d_out, int out_size, void* d_ws, size_t ws_size,
                              hipStream_t stream) {
    const float* x = (const float*)d_in[0];
    const float* w = (const float*)d_in[1];
    float* out = (float*)d_out;

    unsigned short* wb = (unsigned short*)d_ws;                     // 128 KiB
    float* ynK = (float*)((char*)d_ws + (size_t)O_ * C_ * K_ * 2);  // 4 KiB

    prep_w<<<O_, 256, 0, stream>>>(w, wb, ynK);
    shapelet_main<<<N_ * C_, 1024, 0, stream>>>(x, wb, ynK, out);
}